// Round 14
// baseline (1220.948 us; speedup 1.0000x reference)
//
#include <hip/hip_runtime.h>
#include <math.h>

#define BT_TOTAL 4096
#define DD 768
#define TWOD 1536
#define M_MEM 8
#define NHID 16
#define NSY 512
#define K_ITER 8

typedef unsigned short u16;
typedef __attribute__((ext_vector_type(8))) __bf16 bf16x8;
typedef __attribute__((ext_vector_type(4))) float f32x4;

__device__ __forceinline__ float sigmoidf_(float x) {
    return 1.0f / (1.0f + __expf(-x));
}

__device__ __forceinline__ u16 f2bf(float f) {
    unsigned int u = __float_as_uint(f);
    unsigned int r = (u + 0x7FFFu + ((u >> 16) & 1u)) >> 16;
    return (u16)r;
}
__device__ __forceinline__ float bf2f(u16 h) {
    return __uint_as_float(((unsigned int)h) << 16);
}

__device__ __forceinline__ void gload_lds16(const void* g, void* l) {
    __builtin_amdgcn_global_load_lds(
        (const __attribute__((address_space(1))) unsigned int*)g,
        (__attribute__((address_space(3))) unsigned int*)l,
        16, 0, 0);
}

// ---------------------------------------------------------------------------
// init: state hi/lo = split(start_state); alpha = 0
// ---------------------------------------------------------------------------
__global__ __launch_bounds__(256)
void init_kernel(u16* __restrict__ shi, u16* __restrict__ slo,
                 float* __restrict__ alpha, const float* __restrict__ start_state) {
    int idx = blockIdx.x * 256 + threadIdx.x;
    const int nstate = BT_TOTAL * DD;
    if (idx < nstate) {
        float a = start_state[idx % DD];
        u16 h = f2bf(a);
        shi[idx] = h;
        slo[idx] = f2bf(a - bf2f(h));
    } else {
        int a = idx - nstate;
        if (a < BT_TOTAL * NSY) alpha[a] = 0.0f;
    }
}

// ---------------------------------------------------------------------------
// init trace: trace[row][n][j] = start_trace[n][j]  (row-block = flat copy of
// start_trace, 6144 floats). float4 grid-stride.
// ---------------------------------------------------------------------------
__global__ __launch_bounds__(256)
void init_trace_kernel(float* __restrict__ trace, const float* __restrict__ st) {
    const int total4 = BT_TOTAL * DD * M_MEM / 4;   // float4 count
    const int per_row4 = DD * M_MEM / 4;            // 1536
    for (int i = blockIdx.x * 256 + threadIdx.x; i < total4; i += gridDim.x * 256) {
        ((float4*)trace)[i] = ((const float4*)st)[i % per_row4];
    }
}

// ---------------------------------------------------------------------------
// split W_syn halves: wx = W[:, :768], ws = W[:, 768:]  (each 1536x768)
// ---------------------------------------------------------------------------
__global__ __launch_bounds__(256)
void split_w_kernel(const float* __restrict__ W,
                    u16* __restrict__ wxhi, u16* __restrict__ wxlo,
                    u16* __restrict__ wshi, u16* __restrict__ wslo) {
    int idx = blockIdx.x * 256 + threadIdx.x;   // < 1536*768
    int j = idx / DD, k = idx % DD;
    float a = W[(size_t)j * TWOD + k];
    float b = W[(size_t)j * TWOD + DD + k];
    u16 ha = f2bf(a); wxhi[idx] = ha; wxlo[idx] = f2bf(a - bf2f(ha));
    u16 hb = f2bf(b); wshi[idx] = hb; wslo[idx] = f2bf(b - bf2f(hb));
}

// ---------------------------------------------------------------------------
// split x -> xhi, xlo
// ---------------------------------------------------------------------------
__global__ __launch_bounds__(256)
void split_x_kernel(const float* __restrict__ x,
                    u16* __restrict__ xhi, u16* __restrict__ xlo) {
    int idx = blockIdx.x * 256 + threadIdx.x;   // < 4096*768
    float a = x[idx];
    u16 h = f2bf(a);
    xhi[idx] = h;
    xlo[idx] = f2bf(a - bf2f(h));
}

// ---------------------------------------------------------------------------
// wps[d][s] = W_proj[d][s] * rsqrt(beta[s]), written as bf16 hi/lo split
// ---------------------------------------------------------------------------
__global__ __launch_bounds__(256)
void scale_wproj_kernel(const float* __restrict__ wproj,
                        const float* __restrict__ decay,
                        u16* __restrict__ wpshi, u16* __restrict__ wpslo) {
    int idx = blockIdx.x * 256 + threadIdx.x;   // < 768*512
    int s = idx & (NSY - 1);
    float dcl = fminf(fmaxf(decay[s], 0.0f), 15.0f);
    float r = __expf(-dcl);
    float beta = 1.0f, rp = r;
    #pragma unroll
    for (int i = 1; i < K_ITER; ++i) { beta += rp; rp *= r; }
    float w = wproj[idx] * rsqrtf(beta);
    u16 h = f2bf(w);
    wpshi[idx] = h;
    wpslo[idx] = f2bf(w - bf2f(h));
}

// ---------------------------------------------------------------------------
// split alpha -> ahi, alo (for MFMA projection)
// ---------------------------------------------------------------------------
__global__ __launch_bounds__(256)
void split_alpha_kernel(const float* __restrict__ alpha,
                        u16* __restrict__ ahi, u16* __restrict__ alo) {
    int idx = blockIdx.x * 256 + threadIdx.x;   // < 4096*512
    float a = alpha[idx];
    u16 h = f2bf(a);
    ahi[idx] = h;
    alo[idx] = f2bf(a - bf2f(h));
}

// ---------------------------------------------------------------------------
// Split-bf16 MFMA GEMM: C(M x N) = (Ahi+Alo) @ (Bhi+Blo)^T + optional C0.
// A: M x Kdim (lda=Kdim), B: N x Kdim. 128x128 tile, BK=64, 4 waves,
// 16x16x32 bf16 MFMA, 3-term split. XOR-swizzled LDS, pre-swizzled global
// source (rule #21), global_load_lds width 16. Kdim multiple of 64.
// ---------------------------------------------------------------------------
#define TM 128
#define TN 128
#define TK 64

__global__ __launch_bounds__(256)
void gemm_mfma_split(const u16* __restrict__ Ahi, const u16* __restrict__ Alo,
                     const u16* __restrict__ Bhi, const u16* __restrict__ Blo,
                     const float* __restrict__ C0,
                     float* __restrict__ C, int ldc, int ldab, int Kdim) {
    __shared__ u16 sAh[TM * TK];
    __shared__ u16 sAl[TM * TK];
    __shared__ u16 sBh[TN * TK];
    __shared__ u16 sBl[TN * TK];
    const int tid  = threadIdx.x;
    const int w    = tid >> 6;
    const int lane = tid & 63;
    const int row0 = blockIdx.y * TM;
    const int col0 = blockIdx.x * TN;
    const int wr = (w >> 1) * 64;
    const int wc = (w & 1) * 64;

    const f32x4 zero = {0.f, 0.f, 0.f, 0.f};
    f32x4 acc[4][4];
    #pragma unroll
    for (int i = 0; i < 4; ++i)
        #pragma unroll
        for (int j = 0; j < 4; ++j) acc[i][j] = zero;

    const int lr = lane >> 3;
    const int ls = lane & 7;

    for (int kt = 0; kt < Kdim; kt += TK) {
        __syncthreads();
        #pragma unroll
        for (int g = 0; g < 4; ++g) {
            int r  = w * 32 + g * 8 + lr;
            int ss = ls ^ (r & 7);
            size_t goffA = (size_t)(row0 + r) * ldab + kt + ss * 8;
            size_t goffB = (size_t)(col0 + r) * ldab + kt + ss * 8;
            int lo = (w * 32 + g * 8) * TK;
            gload_lds16(Ahi + goffA, &sAh[lo]);
            gload_lds16(Alo + goffA, &sAl[lo]);
            gload_lds16(Bhi + goffB, &sBh[lo]);
            gload_lds16(Blo + goffB, &sBl[lo]);
        }
        __syncthreads();
        #pragma unroll
        for (int ks = 0; ks < 2; ++ks) {
            bf16x8 ah[4], al[4], bh[4], bl[4];
            #pragma unroll
            for (int f = 0; f < 4; ++f) {
                int ra = wr + f * 16 + (lane & 15);
                int sa = (ks * 4 + (lane >> 4)) ^ (ra & 7);
                ah[f] = *(const bf16x8*)(const void*)(sAh + ra * TK + sa * 8);
                al[f] = *(const bf16x8*)(const void*)(sAl + ra * TK + sa * 8);
                int rb = wc + f * 16 + (lane & 15);
                int sb = (ks * 4 + (lane >> 4)) ^ (rb & 7);
                bh[f] = *(const bf16x8*)(const void*)(sBh + rb * TK + sb * 8);
                bl[f] = *(const bf16x8*)(const void*)(sBl + rb * TK + sb * 8);
            }
            #pragma unroll
            for (int i = 0; i < 4; ++i)
                #pragma unroll
                for (int j = 0; j < 4; ++j) {
                    acc[i][j] = __builtin_amdgcn_mfma_f32_16x16x32_bf16(ah[i], bh[j], acc[i][j], 0, 0, 0);
                    acc[i][j] = __builtin_amdgcn_mfma_f32_16x16x32_bf16(ah[i], bl[j], acc[i][j], 0, 0, 0);
                    acc[i][j] = __builtin_amdgcn_mfma_f32_16x16x32_bf16(al[i], bh[j], acc[i][j], 0, 0, 0);
                }
        }
    }

    // epilogue: C/D layout col=lane&15, row=(lane>>4)*4+q  [m89-verified]
    const int cc = lane & 15;
    const int rr = (lane >> 4) * 4;
    #pragma unroll
    for (int i = 0; i < 4; ++i) {
        #pragma unroll
        for (int j = 0; j < 4; ++j) {
            int gr = row0 + wr + i * 16 + rr;
            int gc = col0 + wc + j * 16 + cc;
            #pragma unroll
            for (int q = 0; q < 4; ++q) {
                size_t off = (size_t)(gr + q) * ldc + gc;
                float v = acc[i][j][q];
                if (C0) v += C0[off];
                C[off] = v;
            }
        }
    }
}

// ---------------------------------------------------------------------------
// GLU + LayerNorm, one wave per row. act row: 1536; writes LN output into
// trace slot k: trace[(row*768 + c)*8 + k].
// ---------------------------------------------------------------------------
__global__ __launch_bounds__(256)
void glu_ln_kernel(const float* __restrict__ act,
                   const float* __restrict__ ln_g, const float* __restrict__ ln_b,
                   float* __restrict__ trace, int k) {
    int wave = threadIdx.x >> 6;
    int lane = threadIdx.x & 63;
    int row = blockIdx.x * 4 + wave;
    const float* arow = act + (size_t)row * TWOD;
    float g[12];
    float s = 0.0f, ss = 0.0f;
    #pragma unroll
    for (int q = 0; q < 12; ++q) {
        int c = lane + q * 64;
        float a = arow[c];
        float b = arow[c + DD];
        float v = a * sigmoidf_(b);
        g[q] = v; s += v; ss += v * v;
    }
    #pragma unroll
    for (int off = 32; off; off >>= 1) {
        s  += __shfl_xor(s, off);
        ss += __shfl_xor(ss, off);
    }
    float mu  = s * (1.0f / 768.0f);
    float var = ss * (1.0f / 768.0f) - mu * mu;
    float rstd = rsqrtf(var + 1e-5f);
    float* trow = trace + (size_t)row * DD * M_MEM + k;
    #pragma unroll
    for (int q = 0; q < 12; ++q) {
        int c = lane + q * 64;
        trow[(size_t)c * M_MEM] = (g[q] - mu) * rstd * ln_g[c] + ln_b[c];
    }
}

// ---------------------------------------------------------------------------
// NLM: per-neuron 2-layer GLU MLP over trace window, [row][n][slot] layout.
// Window read = 2 contiguous float4 per (row,n). m->slot rotation
// slot=(m+k+1)&7 absorbed into w1 LDS staging (m=(slot+7-k)&7), so the
// inner loop is branch-free and slot-ordered (fp32 sum reorder only).
// ---------------------------------------------------------------------------
#define NC 16
#define RT 64

__global__ __launch_bounds__(256)
void nlm_kernel(const float* __restrict__ trace,
                const float* __restrict__ w1, const float* __restrict__ b1,
                const float* __restrict__ w2, const float* __restrict__ b2,
                u16* __restrict__ shi, u16* __restrict__ slo, int k) {
    __shared__ float w1s[M_MEM][32][NC];   // 16 KB, slot-major (rotated)
    __shared__ float w2s[NHID][2][NC];     // 2 KB
    __shared__ float b1s[NC][33];
    __shared__ float b2s[NC][3];
    const int tid = threadIdx.x;
    const int n0 = blockIdx.x * NC;
    const int r0 = blockIdx.y * RT;

    for (int idx = tid; idx < M_MEM * 32 * NC; idx += 256) {
        int so = idx / NC;                 // slot*32 + o
        int slot = so >> 5, o = so & 31;
        int nl = idx % NC;
        int m = (slot + 7 - k) & 7;        // rotation: slot=(m+k+1)&7
        w1s[slot][o][nl] = w1[(size_t)(m * 32 + o) * DD + n0 + nl];
    }
    for (int idx = tid; idx < NHID * 2 * NC; idx += 256) {
        int mo = idx / NC, nl = idx % NC;
        ((float*)w2s)[idx] = w2[(size_t)mo * DD + n0 + nl];
    }
    for (int idx = tid; idx < NC * 32; idx += 256) {
        int nl = idx >> 5, o = idx & 31;
        b1s[nl][o] = b1[(size_t)(n0 + nl) * 32 + o];
    }
    if (tid < NC * 2) { int nl = tid >> 1, o = tid & 1; b2s[nl][o] = b2[(size_t)(n0 + nl) * 2 + o]; }
    __syncthreads();

    const int nl = tid & (NC - 1);
    const int n = n0 + nl;
    const int rbase = r0 + (tid >> 4);   // 16 row groups

    // contiguous 32B window loads for 4 rows (stride 16)
    float t[4][M_MEM];
    #pragma unroll
    for (int ri = 0; ri < 4; ++ri) {
        int row = rbase + ri * 16;
        const float* trow = trace + ((size_t)row * DD + n) * M_MEM;
        float4 t0 = *(const float4*)trow;
        float4 t1 = *(const float4*)(trow + 4);
        t[ri][0] = t0.x; t[ri][1] = t0.y; t[ri][2] = t0.z; t[ri][3] = t0.w;
        t[ri][4] = t1.x; t[ri][5] = t1.y; t[ri][6] = t1.z; t[ri][7] = t1.w;
    }

    float p0[4], p1[4];
    #pragma unroll
    for (int ri = 0; ri < 4; ++ri) { p0[ri] = b2s[nl][0]; p1[ri] = b2s[nl][1]; }

    #pragma unroll
    for (int o = 0; o < NHID; ++o) {
        float wa[M_MEM], wb[M_MEM];
        #pragma unroll
        for (int s = 0; s < M_MEM; ++s) {
            wa[s] = w1s[s][o][nl];
            wb[s] = w1s[s][o + 16][nl];
        }
        float w20 = w2s[o][0][nl], w21 = w2s[o][1][nl];
        float ba = b1s[nl][o], bb = b1s[nl][o + 16];
        #pragma unroll
        for (int ri = 0; ri < 4; ++ri) {
            float pa = ba, pb = bb;
            #pragma unroll
            for (int s = 0; s < M_MEM; ++s) {
                pa = fmaf(t[ri][s], wa[s], pa);
                pb = fmaf(t[ri][s], wb[s], pb);
            }
            float h = pa * sigmoidf_(pb);
            p0[ri] = fmaf(h, w20, p0[ri]);
            p1[ri] = fmaf(h, w21, p1[ri]);
        }
    }

    #pragma unroll
    for (int ri = 0; ri < 4; ++ri) {
        int row = rbase + ri * 16;
        float v = p0[ri] * sigmoidf_(p1[ri]);
        size_t off = (size_t)row * DD + n;
        u16 hv = f2bf(v);
        shi[off] = hv;
        slo[off] = f2bf(v - bf2f(hv));
    }
}

// ---------------------------------------------------------------------------
// pp + alpha update. One wave per row. State reconstructed from hi+lo.
// ---------------------------------------------------------------------------
__global__ __launch_bounds__(256)
void pp_kernel(const u16* __restrict__ shi, const u16* __restrict__ slo,
               const float* __restrict__ decay,
               const int* __restrict__ sl, const int* __restrict__ sr,
               float* __restrict__ alpha) {
    __shared__ float srow[4][DD];
    int wave = threadIdx.x >> 6, lane = threadIdx.x & 63;
    int row = blockIdx.x * 4 + wave;
    size_t base = (size_t)row * DD;
    #pragma unroll
    for (int q = 0; q < 12; ++q) {
        int c = lane + q * 64;
        srow[wave][c] = bf2f(shi[base + c]) + bf2f(slo[base + c]);
    }
    __syncthreads();
    float* arow = alpha + (size_t)row * NSY;
    #pragma unroll
    for (int q = 0; q < 8; ++q) {
        int s = lane + q * 64;
        float dcl = fminf(fmaxf(decay[s], 0.0f), 15.0f);
        float r = __expf(-dcl);
        float pp = srow[wave][sl[s]] * srow[wave][sr[s]];
        arow[s] = r * arow[s] + pp;
    }
}

// ---------------------------------------------------------------------------
extern "C" void kernel_launch(void* const* d_in, const int* in_sizes, int n_in,
                              void* d_out, int out_size, void* d_ws, size_t ws_size,
                              hipStream_t stream) {
    const float* x        = (const float*)d_in[0];
    const float* W_syn    = (const float*)d_in[1];
    const float* ln_g     = (const float*)d_in[2];
    const float* ln_b     = (const float*)d_in[3];
    const float* w1       = (const float*)d_in[4];
    const float* b1       = (const float*)d_in[5];
    const float* w2       = (const float*)d_in[6];
    const float* b2       = (const float*)d_in[7];
    const float* start_st = (const float*)d_in[8];
    const float* start_tr = (const float*)d_in[9];
    const float* decay    = (const float*)d_in[10];
    const float* W_proj   = (const float*)d_in[11];
    const int*   sl       = (const int*)d_in[12];
    const int*   sr       = (const int*)d_in[13];
    float* out = (float*)d_out;

    // fp32 region
    float* ws    = (float*)d_ws;
    float* xpre  = ws;                                       // 4096*1536
    float* act   = xpre  + (size_t)BT_TOTAL * TWOD;          // 4096*1536
    float* trace = act   + (size_t)BT_TOTAL * TWOD;          // 4096*768*8
    float* alpha = trace + (size_t)BT_TOTAL * DD * M_MEM;    // 4096*512
    // u16 region (after floats; all offsets 16B-aligned)
    u16* u16base = (u16*)(alpha + (size_t)BT_TOTAL * NSY);
    u16* xhi   = u16base;                                    // 4096*768
    u16* xlo   = xhi   + (size_t)BT_TOTAL * DD;
    u16* shi   = xlo   + (size_t)BT_TOTAL * DD;
    u16* slo   = shi   + (size_t)BT_TOTAL * DD;
    u16* wxhi  = slo   + (size_t)BT_TOTAL * DD;              // 1536*768
    u16* wxlo  = wxhi  + (size_t)TWOD * DD;
    u16* wshi  = wxlo  + (size_t)TWOD * DD;
    u16* wslo  = wshi  + (size_t)TWOD * DD;
    u16* wpshi = wslo  + (size_t)TWOD * DD;                  // 768*512
    u16* wpslo = wpshi + (size_t)DD * NSY;
    u16* ahi   = wpslo + (size_t)DD * NSY;                   // 4096*512
    u16* alo   = ahi   + (size_t)BT_TOTAL * NSY;

    {
        int total = BT_TOTAL * (DD + NSY);
        init_kernel<<<(total + 255) / 256, 256, 0, stream>>>(shi, slo, alpha, start_st);
    }
    init_trace_kernel<<<2048, 256, 0, stream>>>(trace, start_tr);
    split_w_kernel<<<(TWOD * DD) / 256, 256, 0, stream>>>(W_syn, wxhi, wxlo, wshi, wslo);
    split_x_kernel<<<(BT_TOTAL * DD) / 256, 256, 0, stream>>>(x, xhi, xlo);
    scale_wproj_kernel<<<(DD * NSY) / 256, 256, 0, stream>>>(W_proj, decay, wpshi, wpslo);

    // xpre = x @ W_x^T  (split-bf16 MFMA)
    {
        dim3 g(TWOD / TN, BT_TOTAL / TM);
        gemm_mfma_split<<<g, 256, 0, stream>>>(xhi, xlo, wxhi, wxlo, nullptr, xpre, TWOD, DD, DD);
    }

    for (int k = 0; k < K_ITER; ++k) {
        dim3 g(TWOD / TN, BT_TOTAL / TM);
        gemm_mfma_split<<<g, 256, 0, stream>>>(shi, slo, wshi, wslo, xpre, act, TWOD, DD, DD);
        glu_ln_kernel<<<BT_TOTAL / 4, 256, 0, stream>>>(act, ln_g, ln_b, trace, k);
        dim3 gn(DD / NC, BT_TOTAL / RT);
        nlm_kernel<<<gn, 256, 0, stream>>>(trace, w1, b1, w2, b2, shi, slo, k);
        pp_kernel<<<BT_TOTAL / 4, 256, 0, stream>>>(shi, slo, decay, sl, sr, alpha);
    }

    // out = alpha @ wps^T  (split-bf16 MFMA, K=512)
    split_alpha_kernel<<<(BT_TOTAL * NSY) / 256, 256, 0, stream>>>(alpha, ahi, alo);
    {
        dim3 g(DD / TN, BT_TOTAL / TM);
        gemm_mfma_split<<<g, 256, 0, stream>>>(ahi, alo, wpshi, wpslo, nullptr, out, DD, NSY, NSY);
    }
}